// Round 2
// baseline (54820.758 us; speedup 1.0000x reference)
//
#include <hip/hip_runtime.h>
#include <stdint.h>

// DiffusionModel: 1000 sequential forward noise+clip steps + 1 reverse step.
// Reproduces JAX *partitionable* threefry semantics (default since JAX 0.4.36):
//   split(key,n):  child_t = threefry2x32(key, (0, t)); child = (o0, o1)
//   random_bits32: bits[i] = o0 ^ o1 of threefry2x32(key, (0, i))   (XOR-fold)
//   fold_in:       threefry2x32(key, (0, data))
// and XLA ErfInv32 exactly: w = -log1p(-x*x) with log1p emitted as
//   u = 1+m; (u==1) ? m : m*log(u)/(u-1)       [fp contract OFF here]
//
// N = 32*512*512*3 = 25,165,824 elements; each thread owns 2 contiguous
// elements (float2 I/O), 1001 threefry calls per element.

#define NTOTAL 25165824u
#define NPAIR  12582912u
#define TS     1000

__device__ __forceinline__ void tf2x32(uint32_t k0, uint32_t k1,
                                       uint32_t x0, uint32_t x1,
                                       uint32_t& o0, uint32_t& o1) {
  const uint32_t k2 = k0 ^ k1 ^ 0x1BD11BDAu;
  x0 += k0; x1 += k1;
#define RR(r) { x0 += x1; x1 = (x1 << (r)) | (x1 >> (32 - (r))); x1 ^= x0; }
  RR(13) RR(15) RR(26) RR(6)
  x0 += k1; x1 += k2 + 1u;
  RR(17) RR(29) RR(16) RR(24)
  x0 += k2; x1 += k0 + 2u;
  RR(13) RR(15) RR(26) RR(6)
  x0 += k0; x1 += k1 + 3u;
  RR(17) RR(29) RR(16) RR(24)
  x0 += k1; x1 += k2 + 4u;
  RR(13) RR(15) RR(26) RR(6)
  x0 += k2; x1 += k0 + 5u;
#undef RR
  o0 = x0; o1 = x1;
}

// partitionable random_bits(32): counter (0, i), XOR-fold the two outputs.
__device__ __forceinline__ uint32_t tf_bits(uint32_t k0, uint32_t k1, uint32_t i) {
  uint32_t o0, o1;
  tf2x32(k0, k1, 0u, i, o0, o1);
  return o0 ^ o1;
}

// jax _uniform(lo=nextafter(-1,0)=-0.99999994, hi=1): bits>>9 | 1.0f, bitcast,
// -1, then f*(hi-lo)+lo with (hi-lo) == 2.0f exactly in f32 (round-to-even at
// the exact midpoint). f*2 is a power-of-2 mul (exact), so fmaf == mul+add here.
__device__ __forceinline__ float bits_to_u(uint32_t b) {
  float f = __uint_as_float((b >> 9) | 0x3f800000u) - 1.0f;
  float u = fmaf(f, 2.0f, -0.99999994f);
  return fmaxf(-0.99999994f, u);
}

// XLA ErfInv32: w = -log1p(-x*x); branch at w<5 (Giles polynomials).
// log1p per XLA CPU elemental emitter: u=1+m; u==1 ? m : m*log(u)/(u-1).
// fp contract OFF: the reference rounds x*x and 1+m separately — an fma here
// changes u by up to ~8% in the tail (cancellation zone).
__device__ __forceinline__ float erfinv_f(float x) {
#pragma clang fp contract(off)
  float t = x * x;
  float m = -t;
  float u = m + 1.0f;
  float lg;
  if (u == 1.0f) {
    lg = m;
  } else {
    lg = m * __fdividef(__logf(u), u - 1.0f);
  }
  float w = -lg;
  float p;
  if (w < 5.0f) {
    w = w - 2.5f;
    p = 2.81022636e-08f;
    p = fmaf(p, w, 3.43273939e-07f);
    p = fmaf(p, w, -3.5233877e-06f);
    p = fmaf(p, w, -4.39150654e-06f);
    p = fmaf(p, w, 0.00021858087f);
    p = fmaf(p, w, -0.00125372503f);
    p = fmaf(p, w, -0.00417768164f);
    p = fmaf(p, w, 0.246640727f);
    p = fmaf(p, w, 1.50140941f);
  } else {
    w = sqrtf(w) - 3.0f;
    p = -0.000200214257f;
    p = fmaf(p, w, 0.000100950558f);
    p = fmaf(p, w, 0.00134934322f);
    p = fmaf(p, w, -0.00367342844f);
    p = fmaf(p, w, 0.00573950773f);
    p = fmaf(p, w, -0.0076224613f);
    p = fmaf(p, w, 0.00943887047f);
    p = fmaf(p, w, 1.00167406f);
    p = fmaf(p, w, 2.83297682f);
  }
  return p * x;
}

// noise = 0.1f * (sqrt2_f32 * erfinv(u)) — two separate muls (JAX rounding;
// no FP reassociation at default flags so constants stay unfused).
__device__ __forceinline__ float noise_from_bits(uint32_t b) {
  return 0.1f * (1.41421356f * erfinv_f(bits_to_u(b)));
}

__global__ __launch_bounds__(256) void diffusion_kernel(
    const float* __restrict__ x, float* __restrict__ out) {
  // Step keys (partitionable split): key_t = threefry((0,1), (0,t)).
  // Recomputed per block into LDS: 1000 calls over 256 threads ≈ 4/thread.
  __shared__ alignas(16) uint32_t skeys[2 * TS];
  const int tid = threadIdx.x;
  for (int j = tid; j < TS; j += 256) {
    uint32_t o0, o1;
    tf2x32(0u, 1u, 0u, (uint32_t)j, o0, o1);
    skeys[2 * j] = o0;
    skeys[2 * j + 1] = o1;
  }
  __syncthreads();

  const uint32_t i = blockIdx.x * 256u + (uint32_t)tid;
  const uint32_t e0 = 2u * i, e1 = e0 + 1u;

  float2 xv = ((const float2*)x)[i];
  float xa = xv.x, xb = xv.y;

  const uint2* kp = (const uint2*)skeys;
  for (int t = 0; t < TS; ++t) {
    uint2 k = kp[t];  // wave-uniform broadcast ds_read_b64
    float na = noise_from_bits(tf_bits(k.x, k.y, e0));
    float nb = noise_from_bits(tf_bits(k.x, k.y, e1));
    xa = fminf(1.0f, fmaxf(0.0f, xa + na));
    xb = fminf(1.0f, fmaxf(0.0f, xb + nb));
  }

  // rev_key = fold_in(key(2), 999) = threefry((0,2), (0,999)) — fold_in is
  // identical in both threefry modes.
  uint32_t rk0, rk1;
  tf2x32(0u, 2u, 0u, 999u, rk0, rk1);
  float ra = noise_from_bits(tf_bits(rk0, rk1, e0));
  float rb = noise_from_bits(tf_bits(rk0, rk1, e1));
  float2 ov;
  ov.x = fminf(1.0f, fmaxf(0.0f, xa - ra));
  ov.y = fminf(1.0f, fmaxf(0.0f, xb - rb));
  ((float2*)out)[i] = ov;
}

extern "C" void kernel_launch(void* const* d_in, const int* in_sizes, int n_in,
                              void* d_out, int out_size, void* d_ws, size_t ws_size,
                              hipStream_t stream) {
  (void)in_sizes; (void)n_in; (void)d_ws; (void)ws_size; (void)out_size;
  const float* x = (const float*)d_in[0];
  float* out = (float*)d_out;
  dim3 block(256);
  dim3 grid(NPAIR / 256);  // 49152 blocks, 2 elements/thread
  hipLaunchKernelGGL(diffusion_kernel, grid, block, 0, stream, x, out);
}